// Round 1
// baseline (24803.685 us; speedup 1.0000x reference)
//
#include <hip/hip_runtime.h>
#include <math.h>

#define TMAX 197
#define NROW (32 * TMAX)   // 6304
#define NBH  384           // B*H = 32*12
#define QKVD 2304

// ---------------- block reduction helpers (blockDim == 256) ----------------
__device__ __forceinline__ float block_sum(float v, float* red) {
  int tid = threadIdx.x;
#pragma unroll
  for (int off = 32; off; off >>= 1) v += __shfl_xor(v, off);
  __syncthreads();
  if ((tid & 63) == 0) red[tid >> 6] = v;
  __syncthreads();
  float s = red[0];
#pragma unroll
  for (int i = 1; i < 4; ++i) s += red[i];
  return s;
}

__device__ __forceinline__ float block_max(float v, float* red) {
  int tid = threadIdx.x;
#pragma unroll
  for (int off = 32; off; off >>= 1) v = fmaxf(v, __shfl_xor(v, off));
  __syncthreads();
  if ((tid & 63) == 0) red[tid >> 6] = v;
  __syncthreads();
  float s = red[0];
#pragma unroll
  for (int i = 1; i < 4; ++i) s = fmaxf(s, red[i]);
  return s;
}

// ---------------- init ----------------
__global__ void init_kernel(int* Tcur, float* prevm) {
  if (threadIdx.x == 0) { *Tcur = TMAX; *prevm = 1.0f; }
}

// ---------------- patchify: img[B,3,224,224] -> tmp[6272,768] ----------------
__global__ __launch_bounds__(256) void patchify_kernel(const float* __restrict__ img,
                                                       float* __restrict__ outp) {
  int m = blockIdx.x;           // 0..6271
  int b = m / 196, p = m % 196;
  int hp = p / 14, wp = p % 14;
  int tid = threadIdx.x;
  for (int k = tid; k < 768; k += 256) {
    int c = k >> 8, rr = (k >> 4) & 15, cc = k & 15;
    outp[(size_t)m * 768 + k] =
        img[(((size_t)b * 3 + c) * 224 + hp * 16 + rr) * 224 + wp * 16 + cc];
  }
}

// ---------------- cls row: x0[b,0,:] = cls + pos[0] ----------------
__global__ __launch_bounds__(256) void cls_kernel(const float* __restrict__ cls,
                                                  const float* __restrict__ pos,
                                                  float* __restrict__ x0) {
  int b = blockIdx.x;
  int tid = threadIdx.x;
  for (int n = tid; n < 768; n += 256)
    x0[(size_t)b * TMAX * 768 + n] = cls[n] + pos[n];
}

// ---------------- LayerNorm over rows of 768 ----------------
__global__ __launch_bounds__(256) void ln_kernel(const float* __restrict__ X,
                                                 float* __restrict__ Y,
                                                 const float* __restrict__ w,
                                                 const float* __restrict__ b) {
  __shared__ float red[4];
  size_t r = blockIdx.x;
  const float* xr = X + r * 768;
  float* yr = Y + r * 768;
  int tid = threadIdx.x;
  float v0 = xr[tid], v1 = xr[tid + 256], v2 = xr[tid + 512];
  float s = block_sum(v0 + v1 + v2, red);
  float mu = s * (1.f / 768.f);
  float d0 = v0 - mu, d1 = v1 - mu, d2 = v2 - mu;
  float var = block_sum(d0 * d0 + d1 * d1 + d2 * d2, red) * (1.f / 768.f);
  float inv = 1.0f / sqrtf(var + 1e-6f);
  yr[tid]       = d0 * inv * w[tid]       + b[tid];
  yr[tid + 256] = d1 * inv * w[tid + 256] + b[tid + 256];
  yr[tid + 512] = d2 * inv * w[tid + 512] + b[tid + 512];
}

// ---------------- generic fp32 GEMM, 64x64x16 tile ----------------
// mode: 0 = +bias ; 1 = +bias + residual(C+=) ; 2 = gelu(+bias) ; 3 = patch-embed epilogue
__global__ __launch_bounds__(256) void gemm_f32(
    const float* __restrict__ A, long lda,
    const float* __restrict__ Bm, long ldb,
    const float* __restrict__ bias,
    float* __restrict__ C, long ldc,
    int M, int N, int K, int mode, const float* __restrict__ pos) {
  __shared__ float As[16][64];
  __shared__ float Bs[16][64];
  const int tid = threadIdx.x;
  const int tx = tid & 15, ty = tid >> 4;
  const int m0 = blockIdx.y * 64, n0 = blockIdx.x * 64;
  const int arow = tid >> 2, acol = (tid & 3) << 2;
  const int brow = tid >> 4, bcol = (tid & 15) << 2;
  float acc[4][4] = {};
  for (int k0 = 0; k0 < K; k0 += 16) {
    float4 a4 = make_float4(0.f, 0.f, 0.f, 0.f);
    int gm = m0 + arow;
    if (gm < M) a4 = *reinterpret_cast<const float4*>(A + (size_t)gm * lda + k0 + acol);
    As[acol + 0][arow] = a4.x; As[acol + 1][arow] = a4.y;
    As[acol + 2][arow] = a4.z; As[acol + 3][arow] = a4.w;
    float4 b4 = make_float4(0.f, 0.f, 0.f, 0.f);
    int gn = n0 + bcol;
    if (gn < N) b4 = *reinterpret_cast<const float4*>(Bm + (size_t)(k0 + brow) * ldb + gn);
    *reinterpret_cast<float4*>(&Bs[brow][bcol]) = b4;
    __syncthreads();
#pragma unroll
    for (int kk = 0; kk < 16; ++kk) {
      float a[4], bb[4];
#pragma unroll
      for (int i = 0; i < 4; ++i) a[i] = As[kk][(ty << 2) + i];
#pragma unroll
      for (int j = 0; j < 4; ++j) bb[j] = Bs[kk][(tx << 2) + j];
#pragma unroll
      for (int i = 0; i < 4; ++i)
#pragma unroll
        for (int j = 0; j < 4; ++j) acc[i][j] += a[i] * bb[j];
    }
    __syncthreads();
  }
#pragma unroll
  for (int i = 0; i < 4; ++i) {
    int gm = m0 + (ty << 2) + i;
    if (gm >= M) continue;
    size_t crow;
    const float* posrow = nullptr;
    if (mode == 3) {
      int bI = gm / 196, p = gm % 196;
      crow = (size_t)bI * TMAX + 1 + p;
      posrow = pos + (size_t)(1 + p) * 768;
    } else crow = gm;
#pragma unroll
    for (int j = 0; j < 4; ++j) {
      int gn = n0 + (tx << 2) + j;
      if (gn >= N) continue;
      float v = acc[i][j] + bias[gn];
      if (mode == 3) v += posrow[gn];
      if (mode == 2) {
        float u = v;
        v = 0.5f * u * (1.f + tanhf(0.79788456080286535588f * (u + 0.044715f * u * u * u)));
      }
      float* cp = C + crow * ldc + gn;
      if (mode == 1) v += *cp;
      *cp = v;
    }
  }
}

// ---------------- cheap CLS-attention scores (one block per (b,h)) ----------------
__global__ __launch_bounds__(256) void score_kernel(const float* __restrict__ qkv,
                                                    float* __restrict__ av,
                                                    float* __restrict__ entb,
                                                    float* __restrict__ massb,
                                                    const int* __restrict__ Tptr) {
  __shared__ float qs[64];
  __shared__ float red[4];
  __shared__ float lg[TMAX];
  __shared__ float vn[TMAX];
  int T = *Tptr;
  int bh = blockIdx.x;
  int b = bh / 12, h = bh % 12;
  const float* base = qkv + (size_t)b * TMAX * QKVD + h * 64;
  int tid = threadIdx.x;
  if (tid < 64) qs[tid] = base[tid];     // q row of CLS (token 0)
  __syncthreads();
  for (int t = tid; t < T; t += 256) {
    const float* kr = base + (size_t)t * QKVD + 768;
    const float* vr = kr + 768;
    float d = 0.f, v2 = 0.f;
    for (int c = 0; c < 64; ++c) {
      d += qs[c] * kr[c];
      float vv = vr[c];
      v2 += vv * vv;
    }
    lg[t] = d * 0.125f;
    vn[t] = sqrtf(v2);
  }
  __syncthreads();
  float m = -1e30f;
  for (int t = tid; t < T; t += 256) m = fmaxf(m, lg[t]);
  m = block_max(m, red);
  float sum = 0.f;
  for (int t = tid; t < T; t += 256) { float e = expf(lg[t] - m); lg[t] = e; sum += e; }
  sum = block_sum(sum, red);
  float inv = 1.f / sum;
  float ent = 0.f, mp = 0.f;
  for (int t = tid; t < T; t += 256) {
    float a = lg[t] * inv;
    ent += -a * logf(a + 1e-6f);
    if (t >= 1) {
      mp += a;
      av[(size_t)bh * TMAX + t] = a * vn[t];
    }
  }
  ent = block_sum(ent, red);
  mp = block_sum(mp, red);
  if (tid == 0) { entb[bh] = ent; massb[bh] = mp; }
}

// ---------------- decide: keep_ratio, N_next, top-k keep map ----------------
__global__ __launch_bounds__(256) void decide_kernel(const float* __restrict__ av,
                                                     const float* __restrict__ entb,
                                                     const float* __restrict__ massb,
                                                     int* __restrict__ Tcur,
                                                     int* __restrict__ mapv,
                                                     float* __restrict__ prevm) {
  __shared__ float red[4];
  __shared__ float imp[TMAX];
  __shared__ unsigned char keepf[TMAX];
  __shared__ int s_doprune, s_Nn;
  int tid = threadIdx.x;
  int T = *Tcur;
  int N = T - 1;
  float se = 0.f, sm = 0.f;
  for (int i = tid; i < NBH; i += 256) { se += entb[i]; sm += massb[i]; }
  se = block_sum(se, red);
  sm = block_sum(sm, red);
  float mass = sm * (1.f / 384.f);
  float rho = (se * (1.f / 384.f)) / logf((float)T);
  for (int j = tid; j < N; j += 256) {
    float s = 0.f;
    for (int bh = 0; bh < NBH; ++bh) s += av[(size_t)bh * TMAX + 1 + j];
    imp[j] = s * (1.f / 384.f);
  }
  if (tid == 0) {
    int doprune = 0, Nn = N;
    if (N > 16) {
      float kr = 1.0f - 0.01f * rho * (*prevm / (mass + 1e-6f));
      kr = fminf(fmaxf(kr, 0.f), 1.f);
      long nn = (long)((double)N * (double)kr);   // matches Python int(N*float(kr))
      if (nn < 16) nn = 16;
      if (nn < (long)N) { doprune = 1; Nn = (int)nn; }
      *prevm = mass;                               // only updated when N > MIN_TOKENS
    }
    s_doprune = doprune; s_Nn = Nn;
  }
  __syncthreads();
  if (s_doprune) {
    int Nn = s_Nn;
    for (int j = tid; j < N; j += 256) {
      float mj = imp[j];
      int cnt = 0;
      for (int i = 0; i < N; ++i) {
        float v = imp[i];
        cnt += (v > mj) || (v == mj && i < j);
      }
      keepf[j] = (cnt < Nn) ? 1 : 0;
    }
    __syncthreads();
    if (tid == 0) {
      mapv[0] = 0;
      int posi = 1;
      for (int j = 0; j < N; ++j)
        if (keepf[j]) mapv[posi++] = j + 1;
      *Tcur = Nn + 1;
    }
  } else {
    for (int t = tid; t < T; t += 256) mapv[t] = t;
  }
}

// ---------------- gather x rows by keep map ----------------
__global__ __launch_bounds__(256) void gather_kernel(const float* __restrict__ src,
                                                     float* __restrict__ dst,
                                                     const int* __restrict__ Tcur,
                                                     const int* __restrict__ mapv) {
  int t = blockIdx.x;
  if (t >= *Tcur) return;
  int b = blockIdx.y;
  int s = mapv[t];
  const float* sr = src + ((size_t)b * TMAX + s) * 768;
  float* dr = dst + ((size_t)b * TMAX + t) * 768;
  int tid = threadIdx.x;
  dr[tid] = sr[tid];
  dr[tid + 256] = sr[tid + 256];
  dr[tid + 512] = sr[tid + 512];
}

// ---------------- attention (one block per (b,h), K staged transposed in LDS) ----------------
__global__ __launch_bounds__(256) void attn_kernel(const float* __restrict__ qkv,
                                                   float* __restrict__ o,
                                                   const int* __restrict__ Tptr,
                                                   const int* __restrict__ mapv) {
  __shared__ float Kt[64][TMAX];   // 50.4 KB, stride 197 -> conflict-free column reads
  __shared__ float qs[4][64];
  __shared__ float aw[4][TMAX];
  __shared__ int mp[TMAX];
  int T = *Tptr;
  int bh = blockIdx.x;
  int b = bh / 12, h = bh % 12;
  const float* base = qkv + (size_t)b * TMAX * QKVD + h * 64;
  int tid = threadIdx.x;
  for (int t = tid; t < T; t += 256) mp[t] = mapv[t];
  __syncthreads();
  for (int idx = tid; idx < T * 64; idx += 256) {
    int t = idx >> 6, c = idx & 63;
    Kt[c][t] = base[(size_t)mp[t] * QKVD + 768 + c];
  }
  __syncthreads();
  int wid = tid >> 6, lane = tid & 63;
  for (int q0 = 0; q0 < 200; q0 += 4) {
    int q = q0 + wid;
    bool act = (q < T);
    if (act) qs[wid][lane] = base[(size_t)mp[q] * QKVD + lane];
    __syncthreads();
    float inv = 0.f;
    if (act) {
      int k0 = lane, k1 = lane + 64, k2 = lane + 128;
      int k3 = lane + 192; if (k3 > 196) k3 = 196;   // clamp for in-bounds LDS read
      float d0 = 0.f, d1 = 0.f, d2 = 0.f, d3 = 0.f;
      for (int dd = 0; dd < 64; ++dd) {
        float qv = qs[wid][dd];
        d0 += Kt[dd][k0] * qv;
        d1 += Kt[dd][k1] * qv;
        d2 += Kt[dd][k2] * qv;
        d3 += Kt[dd][k3] * qv;
      }
      float s0 = d0 * 0.125f, s1 = d1 * 0.125f, s2 = d2 * 0.125f, s3 = d3 * 0.125f;
      float mx = -1e30f;
      if (k0 < T) mx = fmaxf(mx, s0);
      if (k1 < T) mx = fmaxf(mx, s1);
      if (k2 < T) mx = fmaxf(mx, s2);
      if (lane + 192 < T) mx = fmaxf(mx, s3);
#pragma unroll
      for (int off = 32; off; off >>= 1) mx = fmaxf(mx, __shfl_xor(mx, off));
      float sum = 0.f;
      if (k0 < T) { float e = expf(s0 - mx); aw[wid][k0] = e; sum += e; }
      if (k1 < T) { float e = expf(s1 - mx); aw[wid][k1] = e; sum += e; }
      if (k2 < T) { float e = expf(s2 - mx); aw[wid][k2] = e; sum += e; }
      if (lane + 192 < T) { float e = expf(s3 - mx); aw[wid][lane + 192] = e; sum += e; }
#pragma unroll
      for (int off = 32; off; off >>= 1) sum += __shfl_xor(sum, off);
      inv = 1.f / sum;
    }
    __syncthreads();
    if (act) {
      float acc = 0.f;
      for (int k = 0; k < T; ++k)
        acc += aw[wid][k] * base[(size_t)mp[k] * QKVD + 1536 + lane];
      o[((size_t)b * TMAX + q) * 768 + h * 64 + lane] = acc * inv;
    }
    __syncthreads();
  }
}

// ---------------- launch ----------------
extern "C" void kernel_launch(void* const* d_in, const int* in_sizes, int n_in,
                              void* d_out, int out_size, void* d_ws, size_t ws_size,
                              hipStream_t stream) {
  const float* x       = (const float*)d_in[0];
  const float* patch_w = (const float*)d_in[1];
  const float* patch_b = (const float*)d_in[2];
  const float* cls     = (const float*)d_in[3];
  const float* pos     = (const float*)d_in[4];
  const float* n1w     = (const float*)d_in[5];
  const float* n1b     = (const float*)d_in[6];
  const float* qkv_w   = (const float*)d_in[7];
  const float* qkv_b   = (const float*)d_in[8];
  const float* proj_w  = (const float*)d_in[9];
  const float* proj_b  = (const float*)d_in[10];
  const float* n2w     = (const float*)d_in[11];
  const float* n2b     = (const float*)d_in[12];
  const float* fc1_w   = (const float*)d_in[13];
  const float* fc1_b   = (const float*)d_in[14];
  const float* fc2_w   = (const float*)d_in[15];
  const float* fc2_b   = (const float*)d_in[16];
  const float* nw      = (const float*)d_in[17];
  const float* nb      = (const float*)d_in[18];
  const float* head_w  = (const float*)d_in[19];
  const float* head_b  = (const float*)d_in[20];
  float* out = (float*)d_out;

  float* W = (float*)d_ws;
  size_t o = 0;
  float* x0   = W + o; o += (size_t)NROW * 768;
  float* x1   = W + o; o += (size_t)NROW * 768;
  float* xn   = W + o; o += (size_t)NROW * 768;
  float* qkv0 = W + o; o += (size_t)NROW * QKVD;
  float* hb   = W + o; o += (size_t)NROW * 3072;
  float* av   = W + o; o += (size_t)NBH * TMAX;
  float* entb = W + o; o += NBH;
  float* massb= W + o; o += NBH;
  float* prevm= W + o; o += 1;
  int* Tcur   = (int*)(W + o); o += 1;
  int* mapv   = (int*)(W + o); o += 256;

  init_kernel<<<1, 64, 0, stream>>>(Tcur, prevm);

  // embed: patchify -> tmp(hb) -> GEMM into x0 rows [b*197+1+p] with bias+pos; CLS row separately
  patchify_kernel<<<6272, 256, 0, stream>>>(x, hb);
  gemm_f32<<<dim3(12, 98), 256, 0, stream>>>(hb, 768, patch_w, 768, patch_b,
                                             x0, 768, 6272, 768, 768, 3, pos);
  cls_kernel<<<32, 256, 0, stream>>>(cls, pos, x0);

  for (int l = 0; l < 12; ++l) {
    float* cur = (l & 1) ? x1 : x0;
    float* nxt = (l & 1) ? x0 : x1;
    // LN1 + full-T QKV (shared by score path and block path)
    ln_kernel<<<NROW, 256, 0, stream>>>(cur, xn, n1w + l * 768, n1b + l * 768);
    gemm_f32<<<dim3(36, 99), 256, 0, stream>>>(xn, 768, qkv_w + (size_t)l * 768 * QKVD, QKVD,
                                               qkv_b + l * QKVD, qkv0, QKVD,
                                               NROW, QKVD, 768, 0, nullptr);
    // cheap scores + pruning decision (device-side)
    score_kernel<<<NBH, 256, 0, stream>>>(qkv0, av, entb, massb, Tcur);
    decide_kernel<<<1, 256, 0, stream>>>(av, entb, massb, Tcur, mapv, prevm);
    // gather x rows; attention reads qkv0 through the keep map
    gather_kernel<<<dim3(TMAX, 32), 256, 0, stream>>>(cur, nxt, Tcur, mapv);
    attn_kernel<<<NBH, 256, 0, stream>>>(qkv0, xn, Tcur, mapv);
    gemm_f32<<<dim3(12, 99), 256, 0, stream>>>(xn, 768, proj_w + (size_t)l * 768 * 768, 768,
                                               proj_b + l * 768, nxt, 768,
                                               NROW, 768, 768, 1, nullptr);
    // MLP
    ln_kernel<<<NROW, 256, 0, stream>>>(nxt, xn, n2w + l * 768, n2b + l * 768);
    gemm_f32<<<dim3(48, 99), 256, 0, stream>>>(xn, 768, fc1_w + (size_t)l * 768 * 3072, 3072,
                                               fc1_b + l * 3072, hb, 3072,
                                               NROW, 3072, 768, 2, nullptr);
    gemm_f32<<<dim3(12, 99), 256, 0, stream>>>(hb, 3072, fc2_w + (size_t)l * 3072 * 768, 768,
                                               fc2_b + l * 768, nxt, 768,
                                               NROW, 768, 3072, 1, nullptr);
  }

  // final LN (all rows; only CLS rows consumed) + head
  ln_kernel<<<NROW, 256, 0, stream>>>(x0, xn, nw, nb);
  gemm_f32<<<dim3(16, 1), 256, 0, stream>>>(xn, (long)TMAX * 768, head_w, 1000, head_b,
                                            out, 1000, 32, 1000, 768, 0, nullptr);
}

// Round 5
// 15749.605 us; speedup vs baseline: 1.5749x; 1.5749x over previous
//
#include <hip/hip_runtime.h>
#include <math.h>

#define TMAX 197
#define NROW (32 * TMAX)   // 6304
#define NBH  384           // B*H = 32*12
#define QKVD 2304

typedef __attribute__((ext_vector_type(8))) short s16x8;
typedef __attribute__((ext_vector_type(8))) unsigned short u16x8;
typedef __attribute__((ext_vector_type(4))) float f32x4;

// ---------------- bf16 split helpers ----------------
__device__ __forceinline__ ushort f2bf(float x) {
  unsigned u = __float_as_uint(x);
  unsigned r = (u + 0x7fffu + ((u >> 16) & 1u)) >> 16;
  return (ushort)r;
}
__device__ __forceinline__ float bf2f(ushort h) {
  return __uint_as_float(((unsigned)h) << 16);
}
__device__ __forceinline__ void split2(float x, ushort& h, ushort& l) {
  h = f2bf(x);
  l = f2bf(x - bf2f(h));
}

// ---------------- block reduction helpers (blockDim == 256) ----------------
__device__ __forceinline__ float block_sum(float v, float* red) {
  int tid = threadIdx.x;
#pragma unroll
  for (int off = 32; off; off >>= 1) v += __shfl_xor(v, off);
  __syncthreads();
  if ((tid & 63) == 0) red[tid >> 6] = v;
  __syncthreads();
  float s = red[0];
#pragma unroll
  for (int i = 1; i < 4; ++i) s += red[i];
  return s;
}

__device__ __forceinline__ float block_max(float v, float* red) {
  int tid = threadIdx.x;
#pragma unroll
  for (int off = 32; off; off >>= 1) v = fmaxf(v, __shfl_xor(v, off));
  __syncthreads();
  if ((tid & 63) == 0) red[tid >> 6] = v;
  __syncthreads();
  float s = red[0];
#pragma unroll
  for (int i = 1; i < 4; ++i) s = fmaxf(s, red[i]);
  return s;
}

// ---------------- init ----------------
__global__ void init_kernel(int* Tcur, float* prevm) {
  if (threadIdx.x == 0) { *Tcur = TMAX; *prevm = 1.0f; }
}

// ---------------- patchify: img[B,3,224,224] -> tmp[6272,768] ----------------
__global__ __launch_bounds__(256) void patchify_kernel(const float* __restrict__ img,
                                                       float* __restrict__ outp) {
  int m = blockIdx.x;           // 0..6271
  int b = m / 196, p = m % 196;
  int hp = p / 14, wp = p % 14;
  int tid = threadIdx.x;
  for (int k = tid; k < 768; k += 256) {
    int c = k >> 8, rr = (k >> 4) & 15, cc = k & 15;
    outp[(size_t)m * 768 + k] =
        img[(((size_t)b * 3 + c) * 224 + hp * 16 + rr) * 224 + wp * 16 + cc];
  }
}

// ---------------- cls row: x0[b,0,:] = cls + pos[0] ----------------
__global__ __launch_bounds__(256) void cls_kernel(const float* __restrict__ cls,
                                                  const float* __restrict__ pos,
                                                  float* __restrict__ x0) {
  int b = blockIdx.x;
  int tid = threadIdx.x;
  for (int n = tid; n < 768; n += 256)
    x0[(size_t)b * TMAX * 768 + n] = cls[n] + pos[n];
}

// ---------------- LayerNorm over rows of 768 ----------------
__global__ __launch_bounds__(256) void ln_kernel(const float* __restrict__ X,
                                                 float* __restrict__ Y,
                                                 const float* __restrict__ w,
                                                 const float* __restrict__ b) {
  __shared__ float red[4];
  size_t r = blockIdx.x;
  const float* xr = X + r * 768;
  float* yr = Y + r * 768;
  int tid = threadIdx.x;
  float v0 = xr[tid], v1 = xr[tid + 256], v2 = xr[tid + 512];
  float s = block_sum(v0 + v1 + v2, red);
  float mu = s * (1.f / 768.f);
  float d0 = v0 - mu, d1 = v1 - mu, d2 = v2 - mu;
  float var = block_sum(d0 * d0 + d1 * d1 + d2 * d2, red) * (1.f / 768.f);
  float inv = 1.0f / sqrtf(var + 1e-6f);
  yr[tid]       = d0 * inv * w[tid]       + b[tid];
  yr[tid + 256] = d1 * inv * w[tid + 256] + b[tid + 256];
  yr[tid + 512] = d2 * inv * w[tid + 512] + b[tid + 512];
}

// ---------------- weight transpose + bf16x2 split: W[K][N] -> Th/Tl[N][K] ----------------
__global__ __launch_bounds__(256) void tsplit_kernel(const float* __restrict__ W,
                                                     ushort* __restrict__ Th,
                                                     ushort* __restrict__ Tl,
                                                     int K, int N) {
  __shared__ float t[32][33];
  int tx = threadIdx.x & 31, ty = threadIdx.x >> 5;
  int nt = blockIdx.x * 32, kt = blockIdx.y * 32;
#pragma unroll
  for (int i = 0; i < 4; ++i) {
    int k = kt + ty + i * 8, n = nt + tx;
    t[ty + i * 8][tx] = (k < K && n < N) ? W[(size_t)k * N + n] : 0.f;
  }
  __syncthreads();
#pragma unroll
  for (int i = 0; i < 4; ++i) {
    int n = nt + ty + i * 8, k = kt + tx;
    if (n < N && k < K) {
      float x = t[tx][ty + i * 8];
      ushort h, l;
      split2(x, h, l);
      Th[(size_t)n * K + k] = h;
      Tl[(size_t)n * K + k] = l;
    }
  }
}

// ---------------- MFMA GEMM, bf16x2 split, 128x128x32 tile ----------------
// A: fp32 [M][lda]; B: bf16 hi/lo planes [N][K]. C fp32.
// mode: 0 = +bias ; 1 = +bias + residual(C+=) ; 2 = gelu(+bias) ; 3 = patch-embed epilogue
__global__ __launch_bounds__(256, 2) void gemm_mfma(
    const float* __restrict__ A, long lda,
    const ushort* __restrict__ Bh, const ushort* __restrict__ Bl,
    const float* __restrict__ bias,
    float* __restrict__ C, long ldc,
    int M, int N, int K, int mode, const float* __restrict__ pos) {
  __shared__ ushort As_h[128][40];
  __shared__ ushort As_l[128][40];
  __shared__ ushort Bs_h[128][40];
  __shared__ ushort Bs_l[128][40];
  const int tid = threadIdx.x;
  const int m0 = blockIdx.y * 128, n0 = blockIdx.x * 128;
  const int wid = tid >> 6, lane = tid & 63;
  const int wr = (wid >> 1) * 64, wc = (wid & 1) * 64;
  const int fr = lane & 15, fo = lane >> 4;   // frag row / k-octet
  f32x4 acc[4][4];
#pragma unroll
  for (int i = 0; i < 4; ++i)
#pragma unroll
    for (int j = 0; j < 4; ++j)
#pragma unroll
      for (int e = 0; e < 4; ++e) acc[i][j][e] = 0.f;

  for (int k0 = 0; k0 < K; k0 += 32) {
    // ---- stage A (fp32 -> split bf16x2) ----
#pragma unroll
    for (int g = tid; g < 512; g += 256) {
      int row = g >> 2, ko = g & 3;
      int gm = m0 + row;
      float v[8];
#pragma unroll
      for (int j = 0; j < 8; ++j) v[j] = 0.f;
      if (gm < M) {
        const float* src = A + (size_t)gm * lda + k0 + ko * 8;
        float4 p0 = *reinterpret_cast<const float4*>(src);
        float4 p1 = *reinterpret_cast<const float4*>(src + 4);
        v[0] = p0.x; v[1] = p0.y; v[2] = p0.z; v[3] = p0.w;
        v[4] = p1.x; v[5] = p1.y; v[6] = p1.z; v[7] = p1.w;
      }
      u16x8 hv, lv;
#pragma unroll
      for (int j = 0; j < 8; ++j) {
        ushort h, l;
        split2(v[j], h, l);
        hv[j] = h; lv[j] = l;
      }
      *reinterpret_cast<u16x8*>(&As_h[row][ko * 8]) = hv;
      *reinterpret_cast<u16x8*>(&As_l[row][ko * 8]) = lv;
    }
    // ---- stage B (already split bf16) ----
#pragma unroll
    for (int g = tid; g < 512; g += 256) {
      int row = g >> 2, ko = g & 3;
      int gn = n0 + row;
      u16x8 hv, lv;
#pragma unroll
      for (int j = 0; j < 8; ++j) { hv[j] = 0; lv[j] = 0; }
      if (gn < N) {
        size_t off = (size_t)gn * K + k0 + ko * 8;
        hv = *reinterpret_cast<const u16x8*>(Bh + off);
        lv = *reinterpret_cast<const u16x8*>(Bl + off);
      }
      *reinterpret_cast<u16x8*>(&Bs_h[row][ko * 8]) = hv;
      *reinterpret_cast<u16x8*>(&Bs_l[row][ko * 8]) = lv;
    }
    __syncthreads();
    // ---- fragments + MFMA ----
    s16x8 ah[4], al[4], bh4[4], bl4[4];
#pragma unroll
    for (int mf = 0; mf < 4; ++mf) {
      ah[mf] = *reinterpret_cast<const s16x8*>(&As_h[wr + mf * 16 + fr][fo * 8]);
      al[mf] = *reinterpret_cast<const s16x8*>(&As_l[wr + mf * 16 + fr][fo * 8]);
    }
#pragma unroll
    for (int nf = 0; nf < 4; ++nf) {
      bh4[nf] = *reinterpret_cast<const s16x8*>(&Bs_h[wc + nf * 16 + fr][fo * 8]);
      bl4[nf] = *reinterpret_cast<const s16x8*>(&Bs_l[wc + nf * 16 + fr][fo * 8]);
    }
#pragma unroll
    for (int mf = 0; mf < 4; ++mf)
#pragma unroll
      for (int nf = 0; nf < 4; ++nf) {
        acc[mf][nf] = __builtin_amdgcn_mfma_f32_16x16x32_bf16(ah[mf], bh4[nf], acc[mf][nf], 0, 0, 0);
        acc[mf][nf] = __builtin_amdgcn_mfma_f32_16x16x32_bf16(ah[mf], bl4[nf], acc[mf][nf], 0, 0, 0);
        acc[mf][nf] = __builtin_amdgcn_mfma_f32_16x16x32_bf16(al[mf], bh4[nf], acc[mf][nf], 0, 0, 0);
      }
    __syncthreads();
  }

  // ---- epilogue ----
#pragma unroll
  for (int mf = 0; mf < 4; ++mf)
#pragma unroll
    for (int nf = 0; nf < 4; ++nf) {
      int gn = n0 + wc + nf * 16 + fr;
      if (gn >= N) continue;
      float bs = bias[gn];
#pragma unroll
      for (int j = 0; j < 4; ++j) {
        int gm = m0 + wr + mf * 16 + fo * 4 + j;
        if (gm >= M) continue;
        float v = acc[mf][nf][j] + bs;
        size_t crow;
        if (mode == 3) {
          int bI = gm / 196, p = gm % 196;
          crow = (size_t)bI * TMAX + 1 + p;
          v += pos[(size_t)(1 + p) * 768 + gn];
        } else crow = (size_t)gm;
        if (mode == 2) {
          float u = v;
          v = 0.5f * u * (1.f + tanhf(0.79788456080286535588f * (u + 0.044715f * u * u * u)));
        }
        float* cp = C + crow * ldc + gn;
        if (mode == 1) v += *cp;
        *cp = v;
      }
    }
}

// ---------------- cheap CLS-attention scores (one block per (b,h)) ----------------
__global__ __launch_bounds__(256) void score_kernel(const float* __restrict__ qkv,
                                                    float* __restrict__ av,
                                                    float* __restrict__ entb,
                                                    float* __restrict__ massb,
                                                    const int* __restrict__ Tptr) {
  __shared__ float qs[64];
  __shared__ float red[4];
  __shared__ float lg[TMAX];
  __shared__ float vn[TMAX];
  int T = *Tptr;
  int bh = blockIdx.x;
  int b = bh / 12, h = bh % 12;
  const float* base = qkv + (size_t)b * TMAX * QKVD + h * 64;
  int tid = threadIdx.x;
  if (tid < 64) qs[tid] = base[tid];     // q row of CLS (token 0)
  __syncthreads();
  for (int t = tid; t < T; t += 256) {
    const float* kr = base + (size_t)t * QKVD + 768;
    const float* vr = kr + 768;
    float d = 0.f, v2 = 0.f;
    for (int c = 0; c < 64; ++c) {
      d += qs[c] * kr[c];
      float vv = vr[c];
      v2 += vv * vv;
    }
    lg[t] = d * 0.125f;
    vn[t] = sqrtf(v2);
  }
  __syncthreads();
  float m = -1e30f;
  for (int t = tid; t < T; t += 256) m = fmaxf(m, lg[t]);
  m = block_max(m, red);
  float sum = 0.f;
  for (int t = tid; t < T; t += 256) { float e = expf(lg[t] - m); lg[t] = e; sum += e; }
  sum = block_sum(sum, red);
  float inv = 1.f / sum;
  float ent = 0.f, mp = 0.f;
  for (int t = tid; t < T; t += 256) {
    float a = lg[t] * inv;
    ent += -a * logf(a + 1e-6f);
    if (t >= 1) {
      mp += a;
      av[(size_t)bh * TMAX + t] = a * vn[t];
    }
  }
  ent = block_sum(ent, red);
  mp = block_sum(mp, red);
  if (tid == 0) { entb[bh] = ent; massb[bh] = mp; }
}

// ---------------- decide: keep_ratio, N_next, top-k keep map ----------------
__global__ __launch_bounds__(256) void decide_kernel(const float* __restrict__ av,
                                                     const float* __restrict__ entb,
                                                     const float* __restrict__ massb,
                                                     int* __restrict__ Tcur,
                                                     int* __restrict__ mapv,
                                                     float* __restrict__ prevm) {
  __shared__ float red[4];
  __shared__ float imp[TMAX];
  __shared__ unsigned char keepf[TMAX];
  __shared__ int s_doprune, s_Nn;
  int tid = threadIdx.x;
  int T = *Tcur;
  int N = T - 1;
  float se = 0.f, sm = 0.f;
  for (int i = tid; i < NBH; i += 256) { se += entb[i]; sm += massb[i]; }
  se = block_sum(se, red);
  sm = block_sum(sm, red);
  float mass = sm * (1.f / 384.f);
  float rho = (se * (1.f / 384.f)) / logf((float)T);
  for (int j = tid; j < N; j += 256) {
    float s = 0.f;
    for (int bh = 0; bh < NBH; ++bh) s += av[(size_t)bh * TMAX + 1 + j];
    imp[j] = s * (1.f / 384.f);
  }
  if (tid == 0) {
    int doprune = 0, Nn = N;
    if (N > 16) {
      float kr = 1.0f - 0.01f * rho * (*prevm / (mass + 1e-6f));
      kr = fminf(fmaxf(kr, 0.f), 1.f);
      long nn = (long)((double)N * (double)kr);   // matches Python int(N*float(kr))
      if (nn < 16) nn = 16;
      if (nn < (long)N) { doprune = 1; Nn = (int)nn; }
      *prevm = mass;                               // only updated when N > MIN_TOKENS
    }
    s_doprune = doprune; s_Nn = Nn;
  }
  __syncthreads();
  if (s_doprune) {
    int Nn = s_Nn;
    for (int j = tid; j < N; j += 256) {
      float mj = imp[j];
      int cnt = 0;
      for (int i = 0; i < N; ++i) {
        float v = imp[i];
        cnt += (v > mj) || (v == mj && i < j);
      }
      keepf[j] = (cnt < Nn) ? 1 : 0;
    }
    __syncthreads();
    if (tid == 0) {
      mapv[0] = 0;
      int posi = 1;
      for (int j = 0; j < N; ++j)
        if (keepf[j]) mapv[posi++] = j + 1;
      *Tcur = Nn + 1;
    }
  } else {
    for (int t = tid; t < T; t += 256) mapv[t] = t;
  }
}

// ---------------- gather x rows by keep map ----------------
__global__ __launch_bounds__(256) void gather_kernel(const float* __restrict__ src,
                                                     float* __restrict__ dst,
                                                     const int* __restrict__ Tcur,
                                                     const int* __restrict__ mapv) {
  int t = blockIdx.x;
  if (t >= *Tcur) return;
  int b = blockIdx.y;
  int s = mapv[t];
  const float* sr = src + ((size_t)b * TMAX + s) * 768;
  float* dr = dst + ((size_t)b * TMAX + t) * 768;
  int tid = threadIdx.x;
  dr[tid] = sr[tid];
  dr[tid + 256] = sr[tid + 256];
  dr[tid + 512] = sr[tid + 512];
}

// ---------------- attention (block per (b,h,q-tile), K staged transposed in LDS) ----------------
__global__ __launch_bounds__(256) void attn_kernel(const float* __restrict__ qkv,
                                                   float* __restrict__ o,
                                                   const int* __restrict__ Tptr,
                                                   const int* __restrict__ mapv) {
  __shared__ float Kt[64][TMAX];   // 50.4 KB, stride 197 -> conflict-free column reads
  __shared__ float qs[4][64];
  __shared__ float aw[4][TMAX];
  __shared__ int mp[TMAX];
  int T = *Tptr;
  int bh = blockIdx.x;
  int b = bh / 12, h = bh % 12;
  const float* base = qkv + (size_t)b * TMAX * QKVD + h * 64;
  int tid = threadIdx.x;
  for (int t = tid; t < T; t += 256) mp[t] = mapv[t];
  __syncthreads();
  for (int idx = tid; idx < T * 64; idx += 256) {
    int t = idx >> 6, c = idx & 63;
    Kt[c][t] = base[(size_t)mp[t] * QKVD + 768 + c];
  }
  __syncthreads();
  int wid = tid >> 6, lane = tid & 63;
  int ql = blockIdx.y * 32;
  for (int it = 0; it < 8; ++it) {
    int q = ql + it * 4 + wid;
    bool act = (q < T);
    if (act) qs[wid][lane] = base[(size_t)mp[q] * QKVD + lane];
    __syncthreads();
    float inv = 0.f;
    if (act) {
      int k0 = lane, k1 = lane + 64, k2 = lane + 128;
      int k3 = lane + 192; if (k3 > 196) k3 = 196;   // clamp for in-bounds LDS read
      float d0 = 0.f, d1 = 0.f, d2 = 0.f, d3 = 0.f;
      for (int dd = 0; dd < 64; ++dd) {
        float qv = qs[wid][dd];
        d0 += Kt[dd][k0] * qv;
        d1 += Kt[dd][k1] * qv;
        d2 += Kt[dd][k2] * qv;
        d3 += Kt[dd][k3] * qv;
      }
      float s0 = d0 * 0.125f, s1 = d1 * 0.125f, s2 = d2 * 0.125f, s3 = d3 * 0.125f;
      float mx = -1e30f;
      if (k0 < T) mx = fmaxf(mx, s0);
      if (k1 < T) mx = fmaxf(mx, s1);
      if (k2 < T) mx = fmaxf(mx, s2);
      if (lane + 192 < T) mx = fmaxf(mx, s3);
#pragma unroll
      for (int off = 32; off; off >>= 1) mx = fmaxf(mx, __shfl_xor(mx, off));
      float sum = 0.f;
      if (k0 < T) { float e = expf(s0 - mx); aw[wid][k0] = e; sum += e; }
      if (k1 < T) { float e = expf(s1 - mx); aw[wid][k1] = e; sum += e; }
      if (k2 < T) { float e = expf(s2 - mx); aw[wid][k2] = e; sum += e; }
      if (lane + 192 < T) { float e = expf(s3 - mx); aw[wid][lane + 192] = e; sum += e; }
#pragma unroll
      for (int off = 32; off; off >>= 1) sum += __shfl_xor(sum, off);
      inv = 1.f / sum;
    }
    __syncthreads();
    if (act) {
      float acc = 0.f;
      for (int k = 0; k < T; ++k)
        acc += aw[wid][k] * base[(size_t)mp[k] * QKVD + 1536 + lane];
      o[((size_t)b * TMAX + q) * 768 + h * 64 + lane] = acc * inv;
    }
    __syncthreads();
  }
}

// ---------------- launch ----------------
extern "C" void kernel_launch(void* const* d_in, const int* in_sizes, int n_in,
                              void* d_out, int out_size, void* d_ws, size_t ws_size,
                              hipStream_t stream) {
  const float* x       = (const float*)d_in[0];
  const float* patch_w = (const float*)d_in[1];
  const float* patch_b = (const float*)d_in[2];
  const float* cls     = (const float*)d_in[3];
  const float* pos     = (const float*)d_in[4];
  const float* n1w     = (const float*)d_in[5];
  const float* n1b     = (const float*)d_in[6];
  const float* qkv_w   = (const float*)d_in[7];
  const float* qkv_b   = (const float*)d_in[8];
  const float* proj_w  = (const float*)d_in[9];
  const float* proj_b  = (const float*)d_in[10];
  const float* n2w     = (const float*)d_in[11];
  const float* n2b     = (const float*)d_in[12];
  const float* fc1_w   = (const float*)d_in[13];
  const float* fc1_b   = (const float*)d_in[14];
  const float* fc2_w   = (const float*)d_in[15];
  const float* fc2_b   = (const float*)d_in[16];
  const float* nw      = (const float*)d_in[17];
  const float* nb      = (const float*)d_in[18];
  const float* head_w  = (const float*)d_in[19];
  const float* head_b  = (const float*)d_in[20];
  float* out = (float*)d_out;

  float* W = (float*)d_ws;
  size_t o = 0;
  float* x0   = W + o; o += (size_t)NROW * 768;
  float* x1   = W + o; o += (size_t)NROW * 768;
  float* xn   = W + o; o += (size_t)NROW * 768;
  float* qkv0 = W + o; o += (size_t)NROW * QKVD;
  float* hb   = W + o; o += (size_t)NROW * 3072;
  float* av   = W + o; o += (size_t)NBH * TMAX;
  float* entb = W + o; o += NBH;
  float* massb= W + o; o += NBH;
  float* prevm= W + o; o += 1;
  int* Tcur   = (int*)(W + o); o += 1;
  int* mapv   = (int*)(W + o); o += 256;
  // bf16 split weight buffers (stream-ordered reuse per layer)
  ushort* U = (ushort*)(W + o);
  size_t uo = 0;
  ushort* wtq_h  = U + uo; uo += (size_t)QKVD * 768;
  ushort* wtq_l  = U + uo; uo += (size_t)QKVD * 768;
  ushort* wtp_h  = U + uo; uo += (size_t)768 * 768;
  ushort* wtp_l  = U + uo; uo += (size_t)768 * 768;
  ushort* wtf1_h = U + uo; uo += (size_t)3072 * 768;
  ushort* wtf1_l = U + uo; uo += (size_t)3072 * 768;
  ushort* wtf2_h = U + uo; uo += (size_t)768 * 3072;
  ushort* wtf2_l = U + uo; uo += (size_t)768 * 3072;
  ushort* wtpe_h = U + uo; uo += (size_t)768 * 768;
  ushort* wtpe_l = U + uo; uo += (size_t)768 * 768;
  ushort* wth_h  = U + uo; uo += (size_t)1000 * 768;
  ushort* wth_l  = U + uo; uo += (size_t)1000 * 768;

  init_kernel<<<1, 64, 0, stream>>>(Tcur, prevm);

  // embed: patchify -> hb -> MFMA GEMM into x0 rows [b*197+1+p] (+bias+pos); CLS row separately
  patchify_kernel<<<6272, 256, 0, stream>>>(x, hb);
  tsplit_kernel<<<dim3(24, 24), 256, 0, stream>>>(patch_w, wtpe_h, wtpe_l, 768, 768);
  gemm_mfma<<<dim3(6, 49), 256, 0, stream>>>(hb, 768, wtpe_h, wtpe_l, patch_b,
                                             x0, 768, 6272, 768, 768, 3, pos);
  cls_kernel<<<32, 256, 0, stream>>>(cls, pos, x0);

  for (int l = 0; l < 12; ++l) {
    float* cur = (l & 1) ? x1 : x0;
    float* nxt = (l & 1) ? x0 : x1;
    // LN1 + full-T QKV (shared by score path and block path)
    ln_kernel<<<NROW, 256, 0, stream>>>(cur, xn, n1w + l * 768, n1b + l * 768);
    tsplit_kernel<<<dim3(72, 24), 256, 0, stream>>>(qkv_w + (size_t)l * 768 * QKVD,
                                                    wtq_h, wtq_l, 768, QKVD);
    gemm_mfma<<<dim3(18, 50), 256, 0, stream>>>(xn, 768, wtq_h, wtq_l,
                                                qkv_b + l * QKVD, qkv0, QKVD,
                                                NROW, QKVD, 768, 0, nullptr);
    // cheap scores + pruning decision (device-side)
    score_kernel<<<NBH, 256, 0, stream>>>(qkv0, av, entb, massb, Tcur);
    decide_kernel<<<1, 256, 0, stream>>>(av, entb, massb, Tcur, mapv, prevm);
    // gather x rows; attention reads qkv0 through the keep map
    gather_kernel<<<dim3(TMAX, 32), 256, 0, stream>>>(cur, nxt, Tcur, mapv);
    attn_kernel<<<dim3(NBH, 7), 256, 0, stream>>>(qkv0, xn, Tcur, mapv);
    tsplit_kernel<<<dim3(24, 24), 256, 0, stream>>>(proj_w + (size_t)l * 768 * 768,
                                                    wtp_h, wtp_l, 768, 768);
    gemm_mfma<<<dim3(6, 50), 256, 0, stream>>>(xn, 768, wtp_h, wtp_l,
                                               proj_b + l * 768, nxt, 768,
                                               NROW, 768, 768, 1, nullptr);
    // MLP
    ln_kernel<<<NROW, 256, 0, stream>>>(nxt, xn, n2w + l * 768, n2b + l * 768);
    tsplit_kernel<<<dim3(96, 24), 256, 0, stream>>>(fc1_w + (size_t)l * 768 * 3072,
                                                    wtf1_h, wtf1_l, 768, 3072);
    gemm_mfma<<<dim3(24, 50), 256, 0, stream>>>(xn, 768, wtf1_h, wtf1_l,
                                                fc1_b + l * 3072, hb, 3072,
                                                NROW, 3072, 768, 2, nullptr);
    tsplit_kernel<<<dim3(24, 96), 256, 0, stream>>>(fc2_w + (size_t)l * 3072 * 768,
                                                    wtf2_h, wtf2_l, 3072, 768);
    gemm_mfma<<<dim3(6, 50), 256, 0, stream>>>(hb, 3072, wtf2_h, wtf2_l,
                                               fc2_b + l * 768, nxt, 768,
                                               NROW, 768, 3072, 1, nullptr);
  }

  // final LN (all rows; only CLS rows consumed) + head
  ln_kernel<<<NROW, 256, 0, stream>>>(x0, xn, nw, nb);
  tsplit_kernel<<<dim3(32, 24), 256, 0, stream>>>(head_w, wth_h, wth_l, 768, 1000);
  gemm_mfma<<<dim3(8, 1), 256, 0, stream>>>(xn, (long)TMAX * 768, wth_h, wth_l,
                                            head_b, out, 1000, 32, 1000, 768, 0, nullptr);
}